// Round 1
// baseline (4840.077 us; speedup 1.0000x reference)
//
#include <hip/hip_runtime.h>
#include <hip/hip_bf16.h>
#include <math.h>

#define LSEQ 2048
#define DMODEL 768
#define DINNER 1536
#define DSTATE 16
#define DTRANK 48
#define NLAYER 4
#define XDBL_W 80   /* DTRANK + 2*DSTATE */
#define CH 64       /* scan chunks */
#define SLEN 32     /* steps per chunk, CH*SLEN == LSEQ */

__device__ inline float softplus_f(float x) {
    return fmaxf(x, 0.f) + log1pf(expf(-fabsf(x)));
}
__device__ inline float silu_f(float x) {
    return x / (1.f + expf(-x));
}

/* ---------------- embedding gather ---------------- */
__global__ __launch_bounds__(256) void embed_kernel(
    const int* __restrict__ ids, const float* __restrict__ emb,
    float* __restrict__ x)
{
    int l = blockIdx.x;
    int id = ids[l];
    const float* src = emb + (size_t)id * DMODEL;
    float* dst = x + (size_t)l * DMODEL;
    for (int j = threadIdx.x; j < DMODEL; j += 256) dst[j] = src[j];
}

/* ---------------- rmsnorm (block per row) ---------------- */
__global__ __launch_bounds__(256) void rmsnorm_kernel(
    const float* __restrict__ x, const float* __restrict__ w,
    float* __restrict__ o)
{
    int row = blockIdx.x;
    const float* xr = x + (size_t)row * DMODEL;
    float ss = 0.f;
    for (int j = threadIdx.x; j < DMODEL; j += 256) { float v = xr[j]; ss += v * v; }
    __shared__ float red[256];
    red[threadIdx.x] = ss;
    __syncthreads();
    for (int s = 128; s > 0; s >>= 1) {
        if (threadIdx.x < s) red[threadIdx.x] += red[threadIdx.x + s];
        __syncthreads();
    }
    float scale = rsqrtf(red[0] / DMODEL + 1e-5f);
    for (int j = threadIdx.x; j < DMODEL; j += 256)
        o[(size_t)row * DMODEL + j] = xr[j] * scale * w[j];
}

/* ---------------- generic fp32 GEMM: C[M,N] = A[M,K] * B[N,K]^T ----------------
 * mode 0: store
 * mode 1: softplus(acc + bias[n])
 * mode 2: C += acc  (residual accumulate)
 * Requires K % 16 == 0, A/B rows 16B-aligned at 4-float steps. */
#define BM 64
#define BN 64
#define BK 16
__global__ __launch_bounds__(256) void gemm_nt(
    const float* __restrict__ A, const float* __restrict__ B,
    float* __restrict__ C, int M, int N, int K,
    int lda, int ldb, int ldc, int mode, const float* __restrict__ bias)
{
    __shared__ float As[BK][BM];
    __shared__ float Bs[BK][BN];
    int tid = threadIdx.x;
    int tx = tid & 15;
    int ty = tid >> 4;
    int row0 = blockIdx.y * BM;
    int col0 = blockIdx.x * BN;

    int lm = tid >> 2;          /* 0..63 */
    int lk = (tid & 3) * 4;     /* 0,4,8,12 */

    float acc[4][4];
#pragma unroll
    for (int i = 0; i < 4; ++i)
#pragma unroll
        for (int j = 0; j < 4; ++j) acc[i][j] = 0.f;

    for (int k0 = 0; k0 < K; k0 += BK) {
        {
            int gm = row0 + lm;
            float4 v = make_float4(0.f, 0.f, 0.f, 0.f);
            if (gm < M) v = *(const float4*)(A + (size_t)gm * lda + k0 + lk);
            As[lk + 0][lm] = v.x; As[lk + 1][lm] = v.y;
            As[lk + 2][lm] = v.z; As[lk + 3][lm] = v.w;
            int gn = col0 + lm;
            float4 w = make_float4(0.f, 0.f, 0.f, 0.f);
            if (gn < N) w = *(const float4*)(B + (size_t)gn * ldb + k0 + lk);
            Bs[lk + 0][lm] = w.x; Bs[lk + 1][lm] = w.y;
            Bs[lk + 2][lm] = w.z; Bs[lk + 3][lm] = w.w;
        }
        __syncthreads();
#pragma unroll
        for (int k = 0; k < BK; ++k) {
            float4 a = *(const float4*)(&As[k][ty * 4]);
            float4 b = *(const float4*)(&Bs[k][tx * 4]);
            float av[4] = { a.x, a.y, a.z, a.w };
            float bv[4] = { b.x, b.y, b.z, b.w };
#pragma unroll
            for (int i = 0; i < 4; ++i)
#pragma unroll
                for (int j = 0; j < 4; ++j) acc[i][j] += av[i] * bv[j];
        }
        __syncthreads();
    }

#pragma unroll
    for (int i = 0; i < 4; ++i) {
        int m = row0 + ty * 4 + i;
        if (m >= M) continue;
#pragma unroll
        for (int j = 0; j < 4; ++j) {
            int n = col0 + tx * 4 + j;
            if (n >= N) continue;
            float v = acc[i][j];
            if (mode == 1) v = softplus_f(v + bias[n]);
            else if (mode == 2) v += C[(size_t)m * ldc + n];
            C[(size_t)m * ldc + n] = v;
        }
    }
}

/* ---------------- depthwise causal conv (k=4) + silu ---------------- */
__global__ __launch_bounds__(256) void conv_silu_kernel(
    const float* __restrict__ xr, const float* __restrict__ cw,
    const float* __restrict__ cb, float* __restrict__ u)
{
    int idx = blockIdx.x * 256 + threadIdx.x;
    if (idx >= LSEQ * DINNER) return;
    int l = idx / DINNER;
    int d = idx - l * DINNER;
    float s = cb[d];
#pragma unroll
    for (int t = 0; t < 4; ++t) {
        int ll = l - 3 + t;
        if (ll >= 0) s += xr[(size_t)ll * (2 * DINNER) + d] * cw[d * 4 + t];
    }
    u[idx] = silu_f(s);
}

/* ---------------- A = -exp(A_log) ---------------- */
__global__ __launch_bounds__(256) void neg_exp_kernel(
    const float* __restrict__ a, float* __restrict__ o, int n)
{
    int i = blockIdx.x * 256 + threadIdx.x;
    if (i < n) o[i] = -expf(a[i]);
}

/* ---------------- chunked selective scan ----------------
 * state recurrence per (d,n): h = exp(dt*A)*h + dt*B*u ; y = sum_n h*C
 * phase1: per-chunk affine summary (prodA, scan-from-0)
 * phase2: sequential over chunk summaries -> h at chunk starts
 * phase3: rescan with true start state, reduce over n, gate. */
__global__ __launch_bounds__(256) void scan_phase1(
    const float* __restrict__ delta, const float* __restrict__ u,
    const float* __restrict__ xdbl, const float* __restrict__ Aneg,
    float* __restrict__ cA, float* __restrict__ cB)
{
    int tid = threadIdx.x;
    int n = tid & 15;
    int d = blockIdx.x * 16 + (tid >> 4);
    int c = blockIdx.y;
    float Av = Aneg[d * DSTATE + n];
    float h = 0.f, ap = 1.f;
    int l = c * SLEN;
    for (int s = 0; s < SLEN; ++s, ++l) {
        float dt = delta[(size_t)l * DINNER + d];
        float uv = u[(size_t)l * DINNER + d];
        float Bv = xdbl[l * XDBL_W + DTRANK + n];
        float a = expf(dt * Av);
        h = a * h + dt * Bv * uv;
        ap *= a;
    }
    size_t off = ((size_t)c * DINNER + d) * DSTATE + n;
    cA[off] = ap;
    cB[off] = h;
}

__global__ __launch_bounds__(256) void scan_phase2(
    const float* __restrict__ cA, const float* __restrict__ cB,
    float* __restrict__ hs)
{
    int idx = blockIdx.x * 256 + threadIdx.x; /* over DINNER*DSTATE */
    float h = 0.f;
    for (int c = 0; c < CH; ++c) {
        size_t off = (size_t)c * DINNER * DSTATE + idx;
        hs[off] = h;
        h = cA[off] * h + cB[off];
    }
}

__global__ __launch_bounds__(256) void scan_phase3(
    const float* __restrict__ delta, const float* __restrict__ u,
    const float* __restrict__ xdbl, const float* __restrict__ Aneg,
    const float* __restrict__ hs, const float* __restrict__ Dp,
    const float* __restrict__ xr, float* __restrict__ y)
{
    int tid = threadIdx.x;
    int n = tid & 15;
    int d = blockIdx.x * 16 + (tid >> 4);
    int c = blockIdx.y;
    float Av = Aneg[d * DSTATE + n];
    float Dv = Dp[d];
    float h = hs[((size_t)c * DINNER + d) * DSTATE + n];
    int l = c * SLEN;
    for (int s = 0; s < SLEN; ++s, ++l) {
        float dt = delta[(size_t)l * DINNER + d];
        float uv = u[(size_t)l * DINNER + d];
        float Bv = xdbl[l * XDBL_W + DTRANK + n];
        float Cv = xdbl[l * XDBL_W + DTRANK + DSTATE + n];
        float a = expf(dt * Av);
        h = a * h + dt * Bv * uv;
        float p = h * Cv;
        p += __shfl_down(p, 8, 16);
        p += __shfl_down(p, 4, 16);
        p += __shfl_down(p, 2, 16);
        p += __shfl_down(p, 1, 16);
        if (n == 0) {
            float r = xr[(size_t)l * (2 * DINNER) + DINNER + d];
            y[(size_t)l * DINNER + d] = (p + uv * Dv) * silu_f(r);
        }
    }
}

extern "C" void kernel_launch(void* const* d_in, const int* in_sizes, int n_in,
                              void* d_out, int out_size, void* d_ws, size_t ws_size,
                              hipStream_t stream)
{
    const int*   ids   = (const int*)d_in[0];
    const float* emb   = (const float*)d_in[1];
    const float* in_w  = (const float*)d_in[2];
    const float* cw    = (const float*)d_in[3];
    const float* cb    = (const float*)d_in[4];
    const float* xpw   = (const float*)d_in[5];
    const float* dtw   = (const float*)d_in[6];
    const float* dtb   = (const float*)d_in[7];
    const float* A_log = (const float*)d_in[8];
    const float* Dp    = (const float*)d_in[9];
    const float* ow    = (const float*)d_in[10];
    const float* nw    = (const float*)d_in[11];
    const float* nfw   = (const float*)d_in[12];
    float* out = (float*)d_out;

    float* ws = (float*)d_ws;
    size_t o = 0;
    float* x     = ws + o; o += (size_t)LSEQ * DMODEL;
    float* h     = ws + o; o += (size_t)LSEQ * DMODEL;
    float* xr    = ws + o; o += (size_t)LSEQ * 2 * DINNER;
    float* u     = ws + o; o += (size_t)LSEQ * DINNER;
    float* xdbl  = ws + o; o += (size_t)LSEQ * XDBL_W;
    float* delta = ws + o; o += (size_t)LSEQ * DINNER;
    float* Aneg  = ws + o; o += (size_t)DINNER * DSTATE;
    float* cA    = ws + o; o += (size_t)CH * DINNER * DSTATE;
    float* cB    = ws + o; o += (size_t)CH * DINNER * DSTATE;
    float* hsb   = ws + o; o += (size_t)CH * DINNER * DSTATE;
    float* y     = ws + o; o += (size_t)LSEQ * DINNER;

    const int VOCAB = in_sizes[1] / DMODEL; /* 50264 */

    embed_kernel<<<LSEQ, 256, 0, stream>>>(ids, emb, x);

    for (int i = 0; i < NLAYER; ++i) {
        rmsnorm_kernel<<<LSEQ, 256, 0, stream>>>(x, nw + (size_t)i * DMODEL, h);

        /* x_and_res = h @ in_w^T : (2048,3072) */
        gemm_nt<<<dim3(2 * DINNER / BN, LSEQ / BM), 256, 0, stream>>>(
            h, in_w + (size_t)i * 2 * DINNER * DMODEL, xr,
            LSEQ, 2 * DINNER, DMODEL, DMODEL, DMODEL, 2 * DINNER, 0, nullptr);

        conv_silu_kernel<<<(LSEQ * DINNER + 255) / 256, 256, 0, stream>>>(
            xr, cw + (size_t)i * DINNER * 4, cb + (size_t)i * DINNER, u);

        /* x_dbl = u @ xpw^T : (2048,80) */
        gemm_nt<<<dim3((XDBL_W + BN - 1) / BN, LSEQ / BM), 256, 0, stream>>>(
            u, xpw + (size_t)i * XDBL_W * DINNER, xdbl,
            LSEQ, XDBL_W, DINNER, DINNER, DINNER, XDBL_W, 0, nullptr);

        /* delta = softplus(x_dbl[:, :48] @ dtw^T + dtb) : (2048,1536) */
        gemm_nt<<<dim3(DINNER / BN, LSEQ / BM), 256, 0, stream>>>(
            xdbl, dtw + (size_t)i * DINNER * DTRANK, delta,
            LSEQ, DINNER, DTRANK, XDBL_W, DTRANK, DINNER, 1,
            dtb + (size_t)i * DINNER);

        neg_exp_kernel<<<(DINNER * DSTATE + 255) / 256, 256, 0, stream>>>(
            A_log + (size_t)i * DINNER * DSTATE, Aneg, DINNER * DSTATE);

        scan_phase1<<<dim3(DINNER / 16, CH), 256, 0, stream>>>(
            delta, u, xdbl, Aneg, cA, cB);
        scan_phase2<<<DINNER * DSTATE / 256, 256, 0, stream>>>(cA, cB, hsb);
        scan_phase3<<<dim3(DINNER / 16, CH), 256, 0, stream>>>(
            delta, u, xdbl, Aneg, hsb, Dp + (size_t)i * DINNER, xr, y);

        /* x += y @ ow^T : (2048,768) */
        gemm_nt<<<dim3(DMODEL / BN, LSEQ / BM), 256, 0, stream>>>(
            y, ow + (size_t)i * DMODEL * DINNER, x,
            LSEQ, DMODEL, DINNER, DINNER, DINNER, DMODEL, 2, nullptr);
    }

    rmsnorm_kernel<<<LSEQ, 256, 0, stream>>>(x, nfw, h);

    /* logits = h @ emb^T : (2048, VOCAB) */
    gemm_nt<<<dim3((VOCAB + BN - 1) / BN, LSEQ / BM), 256, 0, stream>>>(
        h, emb, out, LSEQ, VOCAB, DMODEL, DMODEL, DMODEL, VOCAB, 0, nullptr);
}